// Round 1
// baseline (394.853 us; speedup 1.0000x reference)
//
#include <hip/hip_runtime.h>
#include <hip/hip_bf16.h>

#define H_IN 256
#define H    128
#define BN_EPS 1e-5f
#define NCOPY 32
#define NSLICE 256   // edge slices
#define SMAX 5120    // sortb LDS staging capacity (max bucket ~4400)
#define STATS_FLOATS (NCOPY * 2 * H_IN)   // 16384 floats per stats buffer
#define SBLK 512     // stats-role blocks in build_k
#define GEMMB 512    // gemm-role blocks

using u16 = unsigned short;
using u32 = unsigned int;
typedef __attribute__((ext_vector_type(8))) unsigned short us8;
typedef __attribute__((ext_vector_type(8))) short bf16x8;
typedef __attribute__((ext_vector_type(4))) float f32x4;

__device__ __forceinline__ float b2f(u16 u) {
    return __uint_as_float(((u32)u) << 16);
}
__device__ __forceinline__ u16 f2b(float f) {  // round-to-nearest-even
    u32 u = __float_as_uint(f);
    u += 0x7FFF + ((u >> 16) & 1);
    return (u16)(u >> 16);
}

// ---------------- build_k: edge-slice role (deg atomics + col bucket counts)
//                  merged with stats0 role (BN stats over x + x->bf16) ----------------
// grid = NSLICE + SBLK. Roles split by blockIdx; stats buffer statsA pre-zeroed by memset.
__global__ __launch_bounds__(256) void build_k(const int* __restrict__ row,
                                               const int* __restrict__ col,
                                               u32* __restrict__ deg,
                                               u32* __restrict__ bcnt_part,
                                               const float* __restrict__ x,
                                               u16* __restrict__ xb,
                                               float* __restrict__ statsA,
                                               int E, int total4) {
    int tid = threadIdx.x;
    if (blockIdx.x < NSLICE) {
        // ---- edge slice: deg via direct global atomics (200KB, L2-resident),
        //      col coarse-bucket counts via LDS ----
        __shared__ u32 bcnt[256];
        bcnt[tid] = 0;
        __syncthreads();
        int len = (E + NSLICE - 1) / NSLICE;
        int e0 = blockIdx.x * len;
        int e1 = min(e0 + len, E);
        for (int e = e0 + tid; e < e1; e += 256) {
            atomicAdd(&deg[(u32)row[e]], 1u);
            atomicAdd(&bcnt[((u32)col[e]) >> 8], 1u);
        }
        __syncthreads();
        bcnt_part[blockIdx.x * 256 + tid] = bcnt[tid];
    } else {
        // ---- stats0: column sums/sumsq over x (K=256) + fused f32->bf16 ----
        __shared__ float sh[2 * H_IN];
        const int K = H_IN;
        const int csz = 2 * H_IN;
        sh[tid] = 0.f;
        sh[tid + 256] = 0.f;
        __syncthreads();
        int gid = (blockIdx.x - NSLICE) * 256 + tid;
        int stride = SBLK * 256;
        int c0 = (gid * 4) % K;
        float s0=0.f,s1=0.f,s2=0.f,s3=0.f, q0=0.f,q1=0.f,q2=0.f,q3=0.f;
        const float4* A4 = (const float4*)x;
        ushort4* X4 = (ushort4*)xb;
        for (int i = gid; i < total4; i += stride) {
            float4 v = A4[i];
            ushort4 xv;
            xv.x = f2b(v.x); xv.y = f2b(v.y); xv.z = f2b(v.z); xv.w = f2b(v.w);
            X4[i] = xv;
            s0 += v.x; q0 += v.x * v.x;
            s1 += v.y; q1 += v.y * v.y;
            s2 += v.z; q2 += v.z * v.z;
            s3 += v.w; q3 += v.w * v.w;
        }
        atomicAdd(&sh[c0],     s0); atomicAdd(&sh[K + c0],     q0);
        atomicAdd(&sh[c0 + 1], s1); atomicAdd(&sh[K + c0 + 1], q1);
        atomicAdd(&sh[c0 + 2], s2); atomicAdd(&sh[K + c0 + 2], q2);
        atomicAdd(&sh[c0 + 3], s3); atomicAdd(&sh[K + c0 + 3], q3);
        __syncthreads();
        float* dst = statsA + (size_t)((blockIdx.x - NSLICE) & (NCOPY - 1)) * csz;
        for (int i = tid; i < csz; i += 256) atomicAdd(&dst[i], sh[i]);
    }
}

// ---------------- prep_k: scatter role (per-block boff/bbase rescan + edge scatter)
//                  | dinv role | fold0 role. All depend only on build_k. ----------------
// grid = NSLICE + DB + H.
__global__ __launch_bounds__(256) void prep_k(const int* __restrict__ row,
                                              const int* __restrict__ col,
                                              const u32* __restrict__ bcnt_part,
                                              u32* __restrict__ bbase,
                                              u32* __restrict__ ebuf,
                                              const u32* __restrict__ deg,
                                              float* __restrict__ dinv,
                                              const float* __restrict__ W,
                                              const float* __restrict__ stats_mc,
                                              const float* __restrict__ g,
                                              const float* __restrict__ bcoef,
                                              const float* __restrict__ bias,
                                              u16* __restrict__ Wt,
                                              float* __restrict__ bp,
                                              int E, int N, int DB) {
    int tid = threadIdx.x;
    int bx = blockIdx.x;
    if (bx < NSLICE) {
        // ---- scatter: rebuild per-slice cursor = bbase[b] + prefix over earlier slices ----
        __shared__ u32 sc[256];
        __shared__ u32 cur[256];
        int s = bx;
        u32 tot = 0, pre = 0;
        for (int t = 0; t < NSLICE; ++t) {
            u32 v = bcnt_part[t * 256 + tid];   // coalesced, L2-resident (256KB)
            tot += v;
            if (t < s) pre += v;
        }
        sc[tid] = tot;
        __syncthreads();
        for (int o = 1; o < 256; o <<= 1) {
            u32 xv = (tid >= o) ? sc[tid - o] : 0;
            __syncthreads();
            sc[tid] += xv;
            __syncthreads();
        }
        u32 base = sc[tid] - tot;               // exclusive bucket base
        if (s == 0) {
            bbase[tid] = base;
            if (tid == 255) bbase[256] = sc[255];   // == E
        }
        cur[tid] = base + pre;
        __syncthreads();
        int len = (E + NSLICE - 1) / NSLICE;
        int e0 = s * len;
        int e1 = min(e0 + len, E);
        for (int e = e0 + tid; e < e1; e += 256) {
            u32 r = (u32)row[e];
            u32 c = (u32)col[e];
            u32 pos = atomicAdd(&cur[c >> 8], 1u);
            ebuf[pos] = r | ((c & 255u) << 16);
        }
    } else if (bx < NSLICE + DB) {
        // ---- dinv from deg (self-loop => +1) ----
        int n = (bx - NSLICE) * 256 + tid;
        if (n < N) dinv[n] = rsqrtf((float)deg[n] + 1.0f);
    } else {
        // ---- fold0: BN-fold W_feat (K=256) using statsA ----
        int j = bx - NSLICE - DB;
        int k = tid;
        const int K = H_IN;
        const int csz = 2 * H_IN;
        float sum = 0.f, sumsq = 0.f;
#pragma unroll
        for (int c = 0; c < NCOPY; ++c) {
            sum   += stats_mc[(size_t)c * csz + k];
            sumsq += stats_mc[(size_t)c * csz + K + k];
        }
        float mu = sum / (float)N;
        float var = sumsq / (float)N - mu * mu;
        float sK = g[k] * rsqrtf(var + BN_EPS);
        float tK = bcoef[k] - mu * sK;
        float w = W[(size_t)k * H + j];
        Wt[(size_t)j * K + k] = f2b(sK * w);    // transposed: row j contiguous in k
        __shared__ float red[256];
        red[k] = tK * w;
        __syncthreads();
        for (int o = 128; o > 0; o >>= 1) {
            if (k < o) red[k] += red[k + o];
            __syncthreads();
        }
        if (k == 0) bp[j] = bias[j] + red[0];
    }
}

// ---------------- fold for layers 1..3 (K=128, blockDim=K) ----------------
__global__ void fold_k(const float* __restrict__ W, const float* __restrict__ stats_mc,
                       const float* __restrict__ g, const float* __restrict__ b,
                       const float* __restrict__ bias, u16* __restrict__ Wt,
                       float* __restrict__ bp, int N, int K) {
    int j = blockIdx.x;
    int k = threadIdx.x;
    int csz = 2 * K;
    float sum = 0.f, sumsq = 0.f;
#pragma unroll
    for (int c = 0; c < NCOPY; ++c) {
        sum   += stats_mc[(size_t)c * csz + k];
        sumsq += stats_mc[(size_t)c * csz + K + k];
    }
    float mu = sum / (float)N;
    float var = sumsq / (float)N - mu * mu;
    float s = g[k] * rsqrtf(var + BN_EPS);
    float t = b[k] - mu * s;
    float w = W[(size_t)k * H + j];
    Wt[(size_t)j * K + k] = f2b(s * w);
    __shared__ float red[256];
    red[k] = t * w;
    __syncthreads();
    for (int o = blockDim.x >> 1; o > 0; o >>= 1) {
        if (k < o) red[k] += red[k + o];
        __syncthreads();
    }
    if (k == 0) bp[j] = bias[j] + red[0];
}

// ---------------- MFMA GEMM (+ optional sortb role for layer 0) ----------------
// WITH_SORT: blocks [GEMMB, GEMMB+NB) run the per-bucket LDS counting sort -> CSR.
// stats_z (if non-null): block 0 zeroes the NEXT stats buffer (consumed by fold already).
template<int KT, int WITH_SORT>   // KT = K/32
__global__ __launch_bounds__(256) void gemm_mfma_k(const u16* __restrict__ Ab,
                                                   const u16* __restrict__ Wt,
                                                   u16* __restrict__ Yb, int M,
                                                   float* __restrict__ stats_z,
                                                   const u32* __restrict__ ebuf,
                                                   const u32* __restrict__ bbase,
                                                   int* __restrict__ rowptr,
                                                   u16* __restrict__ esrc, int N) {
    int tid = threadIdx.x;
    if constexpr (WITH_SORT != 0) {
        if (blockIdx.x >= GEMMB) {
            // ---- sortb role: per-bucket counting sort -> exact CSR ----
            __shared__ u32 est[SMAX];
            __shared__ u32 hist[256], scanv[256], cur[256];
            int b = blockIdx.x - GEMMB;
            u32 base = bbase[b];
            int size = (int)(bbase[b + 1] - base);
            int st = min(size, SMAX);
            hist[tid] = 0;
            __syncthreads();
            for (int i = tid; i < st; i += 256) {
                u32 e = ebuf[base + i];
                est[i] = e;
                atomicAdd(&hist[(e >> 16) & 255u], 1u);
            }
            for (int i = SMAX + tid; i < size; i += 256) {
                u32 e = ebuf[base + i];
                atomicAdd(&hist[(e >> 16) & 255u], 1u);
            }
            __syncthreads();
            u32 own = hist[tid];
            scanv[tid] = own;
            __syncthreads();
            for (int o = 1; o < 256; o <<= 1) {
                u32 t = (tid >= o) ? scanv[tid - o] : 0;
                __syncthreads();
                scanv[tid] += t;
                __syncthreads();
            }
            u32 excl = scanv[tid] - own;
            int idx = (b << 8) + tid;
            if (idx <= N) rowptr[idx] = (int)(base + excl);
            cur[tid] = excl;
            __syncthreads();
            for (int i = tid; i < st; i += 256) {
                u32 e = est[i];
                u32 pos = atomicAdd(&cur[(e >> 16) & 255u], 1u);
                esrc[base + pos] = (u16)(e & 0xFFFFu);
            }
            for (int i = SMAX + tid; i < size; i += 256) {
                u32 e = ebuf[base + i];
                u32 pos = atomicAdd(&cur[(e >> 16) & 255u], 1u);
                esrc[base + pos] = (u16)(e & 0xFFFFu);
            }
            return;
        }
    }
    const int K = KT * 32;
    if (stats_z && blockIdx.x == 0) {
        for (int i = tid; i < STATS_FLOATS; i += 256) stats_z[i] = 0.f;
    }
    int w = tid >> 6;
    int lane = tid & 63;
    int m16 = lane & 15;
    int q = lane >> 4;

    bf16x8 bfrag[KT][2];
#pragma unroll
    for (int t = 0; t < KT; ++t)
#pragma unroll
        for (int p = 0; p < 2; ++p) {
            int ncol = 32 * w + 16 * p + m16;
            bfrag[t][p] = *(const bf16x8*)(Wt + (size_t)ncol * K + 32 * t + 8 * q);
        }

    int nchunk = M >> 4;
    for (int c = blockIdx.x; c < nchunk; c += GEMMB) {
        int m0 = c << 4;
        const u16* Arow = Ab + (size_t)(m0 + m16) * K + 8 * q;
        bf16x8 afrag[KT];
#pragma unroll
        for (int t = 0; t < KT; ++t)
            afrag[t] = *(const bf16x8*)(Arow + 32 * t);
        f32x4 acc0 = {0.f, 0.f, 0.f, 0.f}, acc1 = {0.f, 0.f, 0.f, 0.f};
#pragma unroll
        for (int t = 0; t < KT; ++t) {
            acc0 = __builtin_amdgcn_mfma_f32_16x16x32_bf16(afrag[t], bfrag[t][0], acc0, 0, 0, 0);
            acc1 = __builtin_amdgcn_mfma_f32_16x16x32_bf16(afrag[t], bfrag[t][1], acc1, 0, 0, 0);
        }
        u16* Crow = Yb + (size_t)(m0 + q * 4) * H + 32 * w + m16;
#pragma unroll
        for (int i = 0; i < 4; ++i) {
            Crow[(size_t)i * H]      = f2b(acc0[i]);
            Crow[(size_t)i * H + 16] = f2b(acc1[i]);
        }
    }
}

// ---------------- CSR aggregation (bf16 gather, u16 esrc, on-the-fly norm) ----------------
__global__ __launch_bounds__(256) void csragg_k(const int* __restrict__ rowptr,
                                                const u16* __restrict__ esrc,
                                                const u16* __restrict__ Yb,
                                                const float* __restrict__ dinv,
                                                const float* __restrict__ bp,
                                                u16* __restrict__ Ob,
                                                float* __restrict__ Of,
                                                float* __restrict__ stats_mc,
                                                int do_stats, int N) {
    __shared__ float sh[1024];                // 4 waves x 256 bins
    int tid = threadIdx.x;
    int node = blockIdx.x * 16 + (tid >> 4);
    int fl = tid & 15;
    float o[8] = {0.f,0.f,0.f,0.f,0.f,0.f,0.f,0.f};
    if (node < N) {
        const us8* Y8 = (const us8*)Yb;
        float dn = dinv[node];
        float acc[8];
        {
            us8 ys = Y8[(size_t)node * 16 + fl];
#pragma unroll
            for (int j = 0; j < 8; ++j) acc[j] = dn * b2f(ys[j]);
        }
        int s = rowptr[node], e = rowptr[node + 1];
        int p = s;
        for (; p + 3 < e; p += 4) {
            int s0 = esrc[p], s1 = esrc[p + 1], s2 = esrc[p + 2], s3 = esrc[p + 3];
            float n0 = dinv[s0], n1 = dinv[s1], n2 = dinv[s2], n3 = dinv[s3];
            us8 v0 = Y8[(size_t)s0 * 16 + fl];
            us8 v1 = Y8[(size_t)s1 * 16 + fl];
            us8 v2 = Y8[(size_t)s2 * 16 + fl];
            us8 v3 = Y8[(size_t)s3 * 16 + fl];
#pragma unroll
            for (int j = 0; j < 8; ++j) acc[j] += n0 * b2f(v0[j]);
#pragma unroll
            for (int j = 0; j < 8; ++j) acc[j] += n1 * b2f(v1[j]);
#pragma unroll
            for (int j = 0; j < 8; ++j) acc[j] += n2 * b2f(v2[j]);
#pragma unroll
            for (int j = 0; j < 8; ++j) acc[j] += n3 * b2f(v3[j]);
        }
        for (; p < e; ++p) {
            int s0 = esrc[p];
            float n0 = dinv[s0];
            us8 v0 = Y8[(size_t)s0 * 16 + fl];
#pragma unroll
            for (int j = 0; j < 8; ++j) acc[j] += n0 * b2f(v0[j]);
        }
        float4 b0 = ((const float4*)bp)[fl * 2];
        float4 b1 = ((const float4*)bp)[fl * 2 + 1];
        o[0] = b0.x + dn * acc[0]; o[1] = b0.y + dn * acc[1];
        o[2] = b0.z + dn * acc[2]; o[3] = b0.w + dn * acc[3];
        o[4] = b1.x + dn * acc[4]; o[5] = b1.y + dn * acc[5];
        o[6] = b1.z + dn * acc[6]; o[7] = b1.w + dn * acc[7];
        if (Of) {
            float4* O4 = (float4*)Of;
            O4[(size_t)node * 32 + fl * 2]     = make_float4(o[0], o[1], o[2], o[3]);
            O4[(size_t)node * 32 + fl * 2 + 1] = make_float4(o[4], o[5], o[6], o[7]);
        } else {
            us8 ov;
#pragma unroll
            for (int j = 0; j < 8; ++j) ov[j] = f2b(o[j]);
            *(us8*)(Ob + (size_t)node * H + fl * 8) = ov;
        }
    }
    if (do_stats) {
        float sv[16];
#pragma unroll
        for (int j = 0; j < 8; ++j) { sv[j] = o[j]; sv[8 + j] = o[j] * o[j]; }
#pragma unroll
        for (int j = 0; j < 16; ++j) {
            sv[j] += __shfl_xor(sv[j], 16, 64);
            sv[j] += __shfl_xor(sv[j], 32, 64);
        }
        int lane = tid & 63, wv = tid >> 6;
        if (lane < 16) {
            float* base = sh + wv * 256;
#pragma unroll
            for (int j = 0; j < 8; ++j) {
                base[fl * 8 + j]       = sv[j];
                base[128 + fl * 8 + j] = sv[8 + j];
            }
        }
        __syncthreads();
        float v = sh[tid] + sh[256 + tid] + sh[512 + tid] + sh[768 + tid];
        atomicAdd(&stats_mc[(size_t)(blockIdx.x & (NCOPY - 1)) * (2 * H) + tid], v);
    }
}

// ---------------- host ----------------
extern "C" void kernel_launch(void* const* d_in, const int* in_sizes, int n_in,
                              void* d_out, int out_size, void* d_ws, size_t ws_size,
                              hipStream_t stream) {
    const float* x     = (const float*)d_in[0];
    const int*   ei    = (const int*)d_in[1];
    const float* bnfg  = (const float*)d_in[2];
    const float* bnfb  = (const float*)d_in[3];
    const float* Wfeat = (const float*)d_in[4];
    const float* bfeat = (const float*)d_in[5];
    const float* bng   = (const float*)d_in[6];
    const float* bnb   = (const float*)d_in[7];
    const float* Ws    = (const float*)d_in[8];
    const float* bs    = (const float*)d_in[9];

    int N = in_sizes[0] / H_IN;      // 50000  (must be < 65536 for u16 esrc)
    int E = in_sizes[1] / 2;         // 800000
    const int* row = ei;
    const int* col = ei + E;

    int NB = (N + 255) >> 8;         // 196 buckets (also dinv blocks)

    char* p = (char*)d_ws;
    auto alloc = [&](size_t bytes) { char* r = p; p += (bytes + 63) & ~size_t(63); return r; };
    // statsA, statsB, deg contiguous -> single memset zeroes all three
    float* statsA    = (float*)alloc(STATS_FLOATS * 4);
    float* statsB    = (float*)alloc(STATS_FLOATS * 4);
    u32*   deg       = (u32*)alloc((size_t)N * 4);
    float* dinv      = (float*)alloc((size_t)N * 4);
    u16*   Wt        = (u16*)alloc(H_IN * H * 2);
    float* bp        = (float*)alloc(H * 4);
    u32*   bcnt_part = (u32*)alloc(NSLICE * 256 * 4);
    u32*   bbase     = (u32*)alloc(257 * 4);
    int*   rowptr    = (int*)alloc((size_t)(N + 1) * 4);
    u32*   ebuf      = (u32*)alloc((size_t)E * 4);
    u16*   esrc      = (u16*)alloc((size_t)E * 2);
    u16*   xb        = (u16*)alloc((size_t)N * H_IN * 2);
    u16*   Yb        = (u16*)alloc((size_t)N * H * 2);
    u16*   ACTb      = (u16*)alloc((size_t)N * H * 2);

    float* out = (float*)d_out;

    // zero statsA + statsB + deg in one shot (graph-capturable)
    hipMemsetAsync(statsA, 0, (size_t)(2 * STATS_FLOATS) * 4 + (size_t)N * 4, stream);

    // edge counting (deg atomics + col buckets) || BN stats over x + x->bf16
    build_k<<<NSLICE + SBLK, 256, 0, stream>>>(row, col, deg, bcnt_part, x, xb, statsA,
                                               E, N * H_IN / 4);
    // scatter (per-block cursor rescan) || dinv || fold0
    prep_k<<<NSLICE + NB + H, 256, 0, stream>>>(row, col, bcnt_part, bbase, ebuf, deg, dinv,
                                                Wfeat, statsA, bnfg, bnfb, bfeat, Wt, bp,
                                                E, N, NB);
    // layer 0 GEMM || per-bucket counting sort -> CSR
    gemm_mfma_k<8, 1><<<GEMMB + NB, 256, 0, stream>>>(xb, Wt, Yb, N, nullptr,
                                                      ebuf, bbase, rowptr, esrc, N);
    // layer 0 aggregation; stats for layer 1 -> statsB (zeroed by memset)
    csragg_k<<<(N + 15) / 16, 256, 0, stream>>>(rowptr, esrc, Yb, dinv, bp,
                                                ACTb, nullptr, statsB, 1, N);

    for (int l = 1; l < 4; ++l) {
        const float* W    = Ws + (size_t)(l - 1) * H * H;
        const float* bias = bs + (size_t)(l - 1) * H;
        const float* g    = bng + (size_t)(l - 1) * H;
        const float* bb   = bnb + (size_t)(l - 1) * H;
        float* sfold   = (l & 1) ? statsB : statsA;              // stats consumed by fold l
        float* szero   = (l == 1) ? statsA : (l == 2) ? statsB : nullptr;  // next csragg target
        float* starget = ((l + 1) & 1) ? statsB : statsA;        // csragg l writes here

        fold_k<<<H, H, 0, stream>>>(W, sfold, g, bb, bias, Wt, bp, N, H);
        gemm_mfma_k<4, 0><<<GEMMB, 256, 0, stream>>>(ACTb, Wt, Yb, N, szero,
                                                     nullptr, nullptr, nullptr, nullptr, N);
        csragg_k<<<(N + 15) / 16, 256, 0, stream>>>(rowptr, esrc, Yb, dinv, bp,
                                                    ACTb, (l == 3) ? out : nullptr,
                                                    starget, (l < 3) ? 1 : 0, N);
    }
}

// Round 2
// 358.083 us; speedup vs baseline: 1.1027x; 1.1027x over previous
//
#include <hip/hip_runtime.h>
#include <hip/hip_bf16.h>

#define H_IN 256
#define H    128
#define BN_EPS 1e-5f
#define NCOPY 32
#define NSLICE 256   // edge slices for bcnt/scatter
#define HSL 32       // edge slices for row histogram
#define QWMAX 8192   // LDS words for quarter histogram (32KB; N<=65535)
#define SMAX 5120    // sortb LDS staging capacity (max bucket ~4400)
#define STATS_FLOATS (NCOPY * 2 * H_IN)   // 16384 floats per stats buffer
#define SBLK 512     // stats-role blocks in build_k
#define GEMMB 512    // gemm-role blocks

using u16 = unsigned short;
using u32 = unsigned int;
typedef __attribute__((ext_vector_type(8))) unsigned short us8;
typedef __attribute__((ext_vector_type(8))) short bf16x8;
typedef __attribute__((ext_vector_type(4))) float f32x4;

__device__ __forceinline__ float b2f(u16 u) {
    return __uint_as_float(((u32)u) << 16);
}
__device__ __forceinline__ u16 f2b(float f) {  // round-to-nearest-even
    u32 u = __float_as_uint(f);
    u += 0x7FFF + ((u >> 16) & 1);
    return (u16)(u >> 16);
}

// ---------------- build_k: three roles ----------------
// [0,NSLICE):          col coarse-bucket counts per slice (LDS)
// [NSLICE,NSLICE+4*HSL): row histogram, slice s=hb>>2, quarter qq=hb&3 (LDS, u16-packed)
// [NSLICE+4*HSL, +SBLK): BN stats over x (K=256) + fused x->bf16
// statsA pre-zeroed by memset. No global atomics anywhere.
__global__ __launch_bounds__(256) void build_k(const int* __restrict__ row,
                                               const int* __restrict__ col,
                                               u32* __restrict__ hist_part,
                                               u32* __restrict__ bcnt_part,
                                               const float* __restrict__ x,
                                               u16* __restrict__ xb,
                                               float* __restrict__ statsA,
                                               int E, int total4, int QW, int qN) {
    __shared__ u32 smem[QWMAX];
    int tid = threadIdx.x;
    int bx = blockIdx.x;
    if (bx < NSLICE) {
        // ---- col bucket counts for slice bx ----
        u32* bcnt = smem;
        bcnt[tid] = 0;
        __syncthreads();
        int len = (E + NSLICE - 1) / NSLICE;
        int e0 = bx * len;
        int e1 = min(e0 + len, E);
        for (int e = e0 + tid; e < e1; e += 256)
            atomicAdd(&bcnt[((u32)col[e]) >> 8], 1u);
        __syncthreads();
        bcnt_part[bx * 256 + tid] = bcnt[tid];
    } else if (bx < NSLICE + 4 * HSL) {
        // ---- row histogram: slice s, quarter qq ----
        int hb = bx - NSLICE;
        int s = hb >> 2;
        int qq = hb & 3;
        u32* hist = smem;
        for (int i = tid; i < QW; i += 256) hist[i] = 0;
        __syncthreads();
        int len = (E + HSL - 1) / HSL;
        int e0 = s * len;
        int e1 = min(e0 + len, E);
        int lo = qq * qN;
        for (int e = e0 + tid; e < e1; e += 256) {
            int r = row[e] - lo;
            if ((u32)r < (u32)qN)
                atomicAdd(&hist[r >> 1], 1u << ((r & 1) << 4));
        }
        __syncthreads();
        u32* dst = hist_part + (size_t)hb * QW;
        for (int i = tid; i < QW; i += 256) dst[i] = hist[i];
    } else {
        // ---- stats0: column sums/sumsq over x (K=256) + fused f32->bf16 ----
        float* sh = (float*)smem;
        const int K = H_IN;
        const int csz = 2 * H_IN;
        sh[tid] = 0.f;
        sh[tid + 256] = 0.f;
        __syncthreads();
        int sb = bx - NSLICE - 4 * HSL;
        int gid = sb * 256 + tid;
        int stride = SBLK * 256;
        int c0 = (gid * 4) & (H_IN - 1);
        float s0=0.f,s1=0.f,s2=0.f,s3=0.f, q0=0.f,q1=0.f,q2=0.f,q3=0.f;
        const float4* A4 = (const float4*)x;
        ushort4* X4 = (ushort4*)xb;
        for (int i = gid; i < total4; i += stride) {
            float4 v = A4[i];
            ushort4 xv;
            xv.x = f2b(v.x); xv.y = f2b(v.y); xv.z = f2b(v.z); xv.w = f2b(v.w);
            X4[i] = xv;
            s0 += v.x; q0 += v.x * v.x;
            s1 += v.y; q1 += v.y * v.y;
            s2 += v.z; q2 += v.z * v.z;
            s3 += v.w; q3 += v.w * v.w;
        }
        atomicAdd(&sh[c0],     s0); atomicAdd(&sh[K + c0],     q0);
        atomicAdd(&sh[c0 + 1], s1); atomicAdd(&sh[K + c0 + 1], q1);
        atomicAdd(&sh[c0 + 2], s2); atomicAdd(&sh[K + c0 + 2], q2);
        atomicAdd(&sh[c0 + 3], s3); atomicAdd(&sh[K + c0 + 3], q3);
        __syncthreads();
        float* dst = statsA + (size_t)(sb & (NCOPY - 1)) * csz;
        for (int i = tid; i < csz; i += 256) atomicAdd(&dst[i], sh[i]);
    }
}

// ---------------- prep_k: scatter role | dinv role (hist reduce) | fold0 role ----------------
// grid = NSLICE + DB + H.
__global__ __launch_bounds__(256) void prep_k(const int* __restrict__ row,
                                              const int* __restrict__ col,
                                              const u32* __restrict__ bcnt_part,
                                              u32* __restrict__ bbase,
                                              u32* __restrict__ ebuf,
                                              const u32* __restrict__ hist_part,
                                              float* __restrict__ dinv,
                                              const float* __restrict__ W,
                                              const float* __restrict__ stats_mc,
                                              const float* __restrict__ g,
                                              const float* __restrict__ bcoef,
                                              const float* __restrict__ bias,
                                              u16* __restrict__ Wt,
                                              float* __restrict__ bp,
                                              int E, int N, int DB, int QW, int qN) {
    int tid = threadIdx.x;
    int bx = blockIdx.x;
    if (bx < NSLICE) {
        // ---- scatter: rebuild per-slice cursor = bbase[b] + prefix over earlier slices ----
        __shared__ u32 sc[256];
        __shared__ u32 cur[256];
        int s = bx;
        u32 tot = 0, pre = 0;
        for (int t = 0; t < NSLICE; ++t) {
            u32 v = bcnt_part[t * 256 + tid];   // coalesced, L2-resident (256KB)
            tot += v;
            if (t < s) pre += v;
        }
        sc[tid] = tot;
        __syncthreads();
        for (int o = 1; o < 256; o <<= 1) {
            u32 xv = (tid >= o) ? sc[tid - o] : 0;
            __syncthreads();
            sc[tid] += xv;
            __syncthreads();
        }
        u32 base = sc[tid] - tot;               // exclusive bucket base
        if (s == 0) {
            bbase[tid] = base;
            if (tid == 255) bbase[256] = sc[255];   // == E
        }
        cur[tid] = base + pre;
        __syncthreads();
        int len = (E + NSLICE - 1) / NSLICE;
        int e0 = s * len;
        int e1 = min(e0 + len, E);
        for (int e = e0 + tid; e < e1; e += 256) {
            u32 r = (u32)row[e];
            u32 c = (u32)col[e];
            u32 pos = atomicAdd(&cur[c >> 8], 1u);
            ebuf[pos] = r | ((c & 255u) << 16);
        }
    } else if (bx < NSLICE + DB) {
        // ---- dinv: reduce quarter histograms across HSL slices ----
        int w = (bx - NSLICE) * 256 + tid;
        if (w < 4 * QW) {
            int qq = w / QW;
            int lw = w - qq * QW;
            u32 v = 0;
            for (int s = 0; s < HSL; ++s)
                v += hist_part[(size_t)(s * 4 + qq) * QW + lw];
            int n = qq * qN + 2 * lw;
            if (n < N)     dinv[n]     = rsqrtf((float)(v & 0xFFFF) + 1.0f);
            if (n + 1 < N) dinv[n + 1] = rsqrtf((float)(v >> 16) + 1.0f);
        }
    } else {
        // ---- fold0: BN-fold W_feat (K=256) using statsA ----
        int j = bx - NSLICE - DB;
        int k = tid;
        const int K = H_IN;
        const int csz = 2 * H_IN;
        float sum = 0.f, sumsq = 0.f;
#pragma unroll
        for (int c = 0; c < NCOPY; ++c) {
            sum   += stats_mc[(size_t)c * csz + k];
            sumsq += stats_mc[(size_t)c * csz + K + k];
        }
        float mu = sum / (float)N;
        float var = sumsq / (float)N - mu * mu;
        float sK = g[k] * rsqrtf(var + BN_EPS);
        float tK = bcoef[k] - mu * sK;
        float w = W[(size_t)k * H + j];
        Wt[(size_t)j * K + k] = f2b(sK * w);    // transposed: row j contiguous in k
        __shared__ float red[256];
        red[k] = tK * w;
        __syncthreads();
        for (int o = 128; o > 0; o >>= 1) {
            if (k < o) red[k] += red[k + o];
            __syncthreads();
        }
        if (k == 0) bp[j] = bias[j] + red[0];
    }
}

// ---------------- fold for layers 1..3 (K=128, blockDim=K) ----------------
__global__ void fold_k(const float* __restrict__ W, const float* __restrict__ stats_mc,
                       const float* __restrict__ g, const float* __restrict__ b,
                       const float* __restrict__ bias, u16* __restrict__ Wt,
                       float* __restrict__ bp, int N, int K) {
    int j = blockIdx.x;
    int k = threadIdx.x;
    int csz = 2 * K;
    float sum = 0.f, sumsq = 0.f;
#pragma unroll
    for (int c = 0; c < NCOPY; ++c) {
        sum   += stats_mc[(size_t)c * csz + k];
        sumsq += stats_mc[(size_t)c * csz + K + k];
    }
    float mu = sum / (float)N;
    float var = sumsq / (float)N - mu * mu;
    float s = g[k] * rsqrtf(var + BN_EPS);
    float t = b[k] - mu * s;
    float w = W[(size_t)k * H + j];
    Wt[(size_t)j * K + k] = f2b(s * w);
    __shared__ float red[256];
    red[k] = t * w;
    __syncthreads();
    for (int o = blockDim.x >> 1; o > 0; o >>= 1) {
        if (k < o) red[k] += red[k + o];
        __syncthreads();
    }
    if (k == 0) bp[j] = bias[j] + red[0];
}

// ---------------- MFMA GEMM (+ optional sortb role for layer 0) ----------------
template<int KT, int WITH_SORT>   // KT = K/32
__global__ __launch_bounds__(256) void gemm_mfma_k(const u16* __restrict__ Ab,
                                                   const u16* __restrict__ Wt,
                                                   u16* __restrict__ Yb, int M,
                                                   float* __restrict__ stats_z,
                                                   const u32* __restrict__ ebuf,
                                                   const u32* __restrict__ bbase,
                                                   int* __restrict__ rowptr,
                                                   u16* __restrict__ esrc, int N) {
    int tid = threadIdx.x;
    if constexpr (WITH_SORT != 0) {
        if (blockIdx.x >= GEMMB) {
            // ---- sortb role: per-bucket counting sort -> exact CSR ----
            __shared__ u32 est[SMAX];
            __shared__ u32 hist[256], scanv[256], cur[256];
            int b = blockIdx.x - GEMMB;
            u32 base = bbase[b];
            int size = (int)(bbase[b + 1] - base);
            int st = min(size, SMAX);
            hist[tid] = 0;
            __syncthreads();
            for (int i = tid; i < st; i += 256) {
                u32 e = ebuf[base + i];
                est[i] = e;
                atomicAdd(&hist[(e >> 16) & 255u], 1u);
            }
            for (int i = SMAX + tid; i < size; i += 256) {
                u32 e = ebuf[base + i];
                atomicAdd(&hist[(e >> 16) & 255u], 1u);
            }
            __syncthreads();
            u32 own = hist[tid];
            scanv[tid] = own;
            __syncthreads();
            for (int o = 1; o < 256; o <<= 1) {
                u32 t = (tid >= o) ? scanv[tid - o] : 0;
                __syncthreads();
                scanv[tid] += t;
                __syncthreads();
            }
            u32 excl = scanv[tid] - own;
            int idx = (b << 8) + tid;
            if (idx <= N) rowptr[idx] = (int)(base + excl);
            cur[tid] = excl;
            __syncthreads();
            for (int i = tid; i < st; i += 256) {
                u32 e = est[i];
                u32 pos = atomicAdd(&cur[(e >> 16) & 255u], 1u);
                esrc[base + pos] = (u16)(e & 0xFFFFu);
            }
            for (int i = SMAX + tid; i < size; i += 256) {
                u32 e = ebuf[base + i];
                u32 pos = atomicAdd(&cur[(e >> 16) & 255u], 1u);
                esrc[base + pos] = (u16)(e & 0xFFFFu);
            }
            return;
        }
    }
    const int K = KT * 32;
    if (stats_z && blockIdx.x == 0) {
        for (int i = tid; i < STATS_FLOATS; i += 256) stats_z[i] = 0.f;
    }
    int w = tid >> 6;
    int lane = tid & 63;
    int m16 = lane & 15;
    int q = lane >> 4;

    bf16x8 bfrag[KT][2];
#pragma unroll
    for (int t = 0; t < KT; ++t)
#pragma unroll
        for (int p = 0; p < 2; ++p) {
            int ncol = 32 * w + 16 * p + m16;
            bfrag[t][p] = *(const bf16x8*)(Wt + (size_t)ncol * K + 32 * t + 8 * q);
        }

    int nchunk = M >> 4;
    for (int c = blockIdx.x; c < nchunk; c += GEMMB) {
        int m0 = c << 4;
        const u16* Arow = Ab + (size_t)(m0 + m16) * K + 8 * q;
        bf16x8 afrag[KT];
#pragma unroll
        for (int t = 0; t < KT; ++t)
            afrag[t] = *(const bf16x8*)(Arow + 32 * t);
        f32x4 acc0 = {0.f, 0.f, 0.f, 0.f}, acc1 = {0.f, 0.f, 0.f, 0.f};
#pragma unroll
        for (int t = 0; t < KT; ++t) {
            acc0 = __builtin_amdgcn_mfma_f32_16x16x32_bf16(afrag[t], bfrag[t][0], acc0, 0, 0, 0);
            acc1 = __builtin_amdgcn_mfma_f32_16x16x32_bf16(afrag[t], bfrag[t][1], acc1, 0, 0, 0);
        }
        u16* Crow = Yb + (size_t)(m0 + q * 4) * H + 32 * w + m16;
#pragma unroll
        for (int i = 0; i < 4; ++i) {
            Crow[(size_t)i * H]      = f2b(acc0[i]);
            Crow[(size_t)i * H + 16] = f2b(acc1[i]);
        }
    }
}

// ---------------- CSR aggregation (bf16 gather, u16 esrc, on-the-fly norm) ----------------
__global__ __launch_bounds__(256) void csragg_k(const int* __restrict__ rowptr,
                                                const u16* __restrict__ esrc,
                                                const u16* __restrict__ Yb,
                                                const float* __restrict__ dinv,
                                                const float* __restrict__ bp,
                                                u16* __restrict__ Ob,
                                                float* __restrict__ Of,
                                                float* __restrict__ stats_mc,
                                                int do_stats, int N) {
    __shared__ float sh[1024];                // 4 waves x 256 bins
    int tid = threadIdx.x;
    int node = blockIdx.x * 16 + (tid >> 4);
    int fl = tid & 15;
    float o[8] = {0.f,0.f,0.f,0.f,0.f,0.f,0.f,0.f};
    if (node < N) {
        const us8* Y8 = (const us8*)Yb;
        float dn = dinv[node];
        float acc[8];
        {
            us8 ys = Y8[(size_t)node * 16 + fl];
#pragma unroll
            for (int j = 0; j < 8; ++j) acc[j] = dn * b2f(ys[j]);
        }
        int s = rowptr[node], e = rowptr[node + 1];
        int p = s;
        for (; p + 3 < e; p += 4) {
            int s0 = esrc[p], s1 = esrc[p + 1], s2 = esrc[p + 2], s3 = esrc[p + 3];
            float n0 = dinv[s0], n1 = dinv[s1], n2 = dinv[s2], n3 = dinv[s3];
            us8 v0 = Y8[(size_t)s0 * 16 + fl];
            us8 v1 = Y8[(size_t)s1 * 16 + fl];
            us8 v2 = Y8[(size_t)s2 * 16 + fl];
            us8 v3 = Y8[(size_t)s3 * 16 + fl];
#pragma unroll
            for (int j = 0; j < 8; ++j) acc[j] += n0 * b2f(v0[j]);
#pragma unroll
            for (int j = 0; j < 8; ++j) acc[j] += n1 * b2f(v1[j]);
#pragma unroll
            for (int j = 0; j < 8; ++j) acc[j] += n2 * b2f(v2[j]);
#pragma unroll
            for (int j = 0; j < 8; ++j) acc[j] += n3 * b2f(v3[j]);
        }
        for (; p < e; ++p) {
            int s0 = esrc[p];
            float n0 = dinv[s0];
            us8 v0 = Y8[(size_t)s0 * 16 + fl];
#pragma unroll
            for (int j = 0; j < 8; ++j) acc[j] += n0 * b2f(v0[j]);
        }
        float4 b0 = ((const float4*)bp)[fl * 2];
        float4 b1 = ((const float4*)bp)[fl * 2 + 1];
        o[0] = b0.x + dn * acc[0]; o[1] = b0.y + dn * acc[1];
        o[2] = b0.z + dn * acc[2]; o[3] = b0.w + dn * acc[3];
        o[4] = b1.x + dn * acc[4]; o[5] = b1.y + dn * acc[5];
        o[6] = b1.z + dn * acc[6]; o[7] = b1.w + dn * acc[7];
        if (Of) {
            float4* O4 = (float4*)Of;
            O4[(size_t)node * 32 + fl * 2]     = make_float4(o[0], o[1], o[2], o[3]);
            O4[(size_t)node * 32 + fl * 2 + 1] = make_float4(o[4], o[5], o[6], o[7]);
        } else {
            us8 ov;
#pragma unroll
            for (int j = 0; j < 8; ++j) ov[j] = f2b(o[j]);
            *(us8*)(Ob + (size_t)node * H + fl * 8) = ov;
        }
    }
    if (do_stats) {
        float sv[16];
#pragma unroll
        for (int j = 0; j < 8; ++j) { sv[j] = o[j]; sv[8 + j] = o[j] * o[j]; }
#pragma unroll
        for (int j = 0; j < 16; ++j) {
            sv[j] += __shfl_xor(sv[j], 16, 64);
            sv[j] += __shfl_xor(sv[j], 32, 64);
        }
        int lane = tid & 63, wv = tid >> 6;
        if (lane < 16) {
            float* base = sh + wv * 256;
#pragma unroll
            for (int j = 0; j < 8; ++j) {
                base[fl * 8 + j]       = sv[j];
                base[128 + fl * 8 + j] = sv[8 + j];
            }
        }
        __syncthreads();
        float v = sh[tid] + sh[256 + tid] + sh[512 + tid] + sh[768 + tid];
        atomicAdd(&stats_mc[(size_t)(blockIdx.x & (NCOPY - 1)) * (2 * H) + tid], v);
    }
}

// ---------------- host ----------------
extern "C" void kernel_launch(void* const* d_in, const int* in_sizes, int n_in,
                              void* d_out, int out_size, void* d_ws, size_t ws_size,
                              hipStream_t stream) {
    const float* x     = (const float*)d_in[0];
    const int*   ei    = (const int*)d_in[1];
    const float* bnfg  = (const float*)d_in[2];
    const float* bnfb  = (const float*)d_in[3];
    const float* Wfeat = (const float*)d_in[4];
    const float* bfeat = (const float*)d_in[5];
    const float* bng   = (const float*)d_in[6];
    const float* bnb   = (const float*)d_in[7];
    const float* Ws    = (const float*)d_in[8];
    const float* bs    = (const float*)d_in[9];

    int N = in_sizes[0] / H_IN;      // 50000  (must be < 65536 for u16 esrc)
    int E = in_sizes[1] / 2;         // 800000
    const int* row = ei;
    const int* col = ei + E;

    int NB = (N + 255) >> 8;         // 196 buckets
    int QW = (N + 7) / 8;            // 6250 words per quarter histogram
    int qN = 2 * QW;                 // 12500 rows per quarter
    int DB = (4 * QW + 255) / 256;   // 98 dinv blocks

    char* p = (char*)d_ws;
    auto alloc = [&](size_t bytes) { char* r = p; p += (bytes + 63) & ~size_t(63); return r; };
    float* statsA    = (float*)alloc(STATS_FLOATS * 4);
    float* statsB    = (float*)alloc(STATS_FLOATS * 4);
    float* dinv      = (float*)alloc((size_t)N * 4);
    u16*   Wt        = (u16*)alloc(H_IN * H * 2);
    float* bp        = (float*)alloc(H * 4);
    u32*   hist_part = (u32*)alloc((size_t)4 * HSL * QW * 4);   // 3.2MB
    u32*   bcnt_part = (u32*)alloc(NSLICE * 256 * 4);
    u32*   bbase     = (u32*)alloc(257 * 4);
    int*   rowptr    = (int*)alloc((size_t)(N + 1) * 4);
    u32*   ebuf      = (u32*)alloc((size_t)E * 4);
    u16*   esrc      = (u16*)alloc((size_t)E * 2);
    u16*   xb        = (u16*)alloc((size_t)N * H_IN * 2);
    u16*   Yb        = (u16*)alloc((size_t)N * H * 2);
    u16*   ACTb      = (u16*)alloc((size_t)N * H * 2);

    float* out = (float*)d_out;

    // zero statsA + statsB (128KB)
    hipMemsetAsync(statsA, 0, (size_t)(2 * STATS_FLOATS) * 4, stream);

    // col bucket counts || row quarter-histograms || BN stats over x + x->bf16
    build_k<<<NSLICE + 4 * HSL + SBLK, 256, 0, stream>>>(row, col, hist_part, bcnt_part,
                                                         x, xb, statsA, E, N * H_IN / 4,
                                                         QW, qN);
    // scatter (per-block cursor rescan) || dinv (hist reduce) || fold0
    prep_k<<<NSLICE + DB + H, 256, 0, stream>>>(row, col, bcnt_part, bbase, ebuf,
                                                hist_part, dinv,
                                                Wfeat, statsA, bnfg, bnfb, bfeat, Wt, bp,
                                                E, N, DB, QW, qN);
    // layer 0 GEMM || per-bucket counting sort -> CSR
    gemm_mfma_k<8, 1><<<GEMMB + NB, 256, 0, stream>>>(xb, Wt, Yb, N, nullptr,
                                                      ebuf, bbase, rowptr, esrc, N);
    // layer 0 aggregation; stats for layer 1 -> statsB (zeroed by memset)
    csragg_k<<<(N + 15) / 16, 256, 0, stream>>>(rowptr, esrc, Yb, dinv, bp,
                                                ACTb, nullptr, statsB, 1, N);

    for (int l = 1; l < 4; ++l) {
        const float* W    = Ws + (size_t)(l - 1) * H * H;
        const float* bias = bs + (size_t)(l - 1) * H;
        const float* g    = bng + (size_t)(l - 1) * H;
        const float* bb   = bnb + (size_t)(l - 1) * H;
        float* sfold   = (l & 1) ? statsB : statsA;              // stats consumed by fold l
        float* szero   = (l == 1) ? statsA : (l == 2) ? statsB : nullptr;  // next csragg target
        float* starget = ((l + 1) & 1) ? statsB : statsA;        // csragg l writes here

        fold_k<<<H, H, 0, stream>>>(W, sfold, g, bb, bias, Wt, bp, N, H);
        gemm_mfma_k<4, 0><<<GEMMB, 256, 0, stream>>>(ACTb, Wt, Yb, N, szero,
                                                     nullptr, nullptr, nullptr, nullptr, N);
        csragg_k<<<(N + 15) / 16, 256, 0, stream>>>(rowptr, esrc, Yb, dinv, bp,
                                                    ACTb, (l == 3) ? out : nullptr,
                                                    starget, (l < 3) ? 1 : 0, N);
    }
}

// Round 3
// 340.650 us; speedup vs baseline: 1.1591x; 1.0512x over previous
//
#include <hip/hip_runtime.h>
#include <hip/hip_bf16.h>

#define H_IN 256
#define H    128
#define BN_EPS 1e-5f
#define NCOPY 32
#define NSLICE 256   // edge slices for bcnt/scatter
#define HSL 64       // edge slices for row histogram
#define SMAX 5120    // sortb LDS staging capacity (max bucket ~4400)
#define STATS_FLOATS (NCOPY * 2 * H_IN)   // 16384 floats per stats buffer
#define SBLK 1024    // stats-role blocks in build_k
#define GEMMB 512    // gemm-role blocks

using u16 = unsigned short;
using u32 = unsigned int;
typedef __attribute__((ext_vector_type(8))) unsigned short us8;
typedef __attribute__((ext_vector_type(8))) short bf16x8;
typedef __attribute__((ext_vector_type(4))) float f32x4;

__device__ __forceinline__ float b2f(u16 u) {
    return __uint_as_float(((u32)u) << 16);
}
__device__ __forceinline__ u16 f2b(float f) {  // round-to-nearest-even
    u32 u = __float_as_uint(f);
    u += 0x7FFF + ((u >> 16) & 1);
    return (u16)(u >> 16);
}

// ---------------- build_k: three roles, all 4-way ILP-batched ----------------
// [0,NSLICE):            col coarse-bucket counts per slice (LDS)
// [NSLICE,NSLICE+4*HSL): row histogram, slice s=hb>>2, quarter qq=hb&3 (LDS, u16-packed)
// [NSLICE+4*HSL,+SBLK):  BN stats over x (K=256) + fused x->bf16
// Dynamic LDS = QW*4 bytes (~25KB) -> 6 blocks/CU.
__global__ __launch_bounds__(256) void build_k(const int* __restrict__ row,
                                               const int* __restrict__ col,
                                               u32* __restrict__ hist_part,
                                               u32* __restrict__ bcnt_part,
                                               const float* __restrict__ x,
                                               u16* __restrict__ xb,
                                               float* __restrict__ statsA,
                                               int E, int total4, int QW, int qN) {
    extern __shared__ u32 smem[];
    int tid = threadIdx.x;
    int bx = blockIdx.x;
    if (bx < NSLICE) {
        // ---- col bucket counts for slice bx ----
        u32* bcnt = smem;
        bcnt[tid] = 0;
        __syncthreads();
        int len = (E + NSLICE - 1) / NSLICE;
        int e0 = bx * len;
        int e1 = min(e0 + len, E);
        int e = e0 + tid;
        for (; e + 3 * 256 < e1; e += 4 * 256) {
            u32 c0 = (u32)col[e];
            u32 c1 = (u32)col[e + 256];
            u32 c2 = (u32)col[e + 512];
            u32 c3 = (u32)col[e + 768];
            atomicAdd(&bcnt[c0 >> 8], 1u);
            atomicAdd(&bcnt[c1 >> 8], 1u);
            atomicAdd(&bcnt[c2 >> 8], 1u);
            atomicAdd(&bcnt[c3 >> 8], 1u);
        }
        for (; e < e1; e += 256)
            atomicAdd(&bcnt[((u32)col[e]) >> 8], 1u);
        __syncthreads();
        bcnt_part[bx * 256 + tid] = bcnt[tid];
    } else if (bx < NSLICE + 4 * HSL) {
        // ---- row histogram: slice s, quarter qq ----
        int hb = bx - NSLICE;
        int s = hb >> 2;
        int qq = hb & 3;
        u32* hist = smem;
        for (int i = tid; i < QW; i += 256) hist[i] = 0;
        __syncthreads();
        int len = (E + HSL - 1) / HSL;
        int e0 = s * len;
        int e1 = min(e0 + len, E);
        int lo = qq * qN;
        int e = e0 + tid;
        for (; e + 3 * 256 < e1; e += 4 * 256) {
            int r0 = row[e] - lo;
            int r1 = row[e + 256] - lo;
            int r2 = row[e + 512] - lo;
            int r3 = row[e + 768] - lo;
            if ((u32)r0 < (u32)qN) atomicAdd(&hist[r0 >> 1], 1u << ((r0 & 1) << 4));
            if ((u32)r1 < (u32)qN) atomicAdd(&hist[r1 >> 1], 1u << ((r1 & 1) << 4));
            if ((u32)r2 < (u32)qN) atomicAdd(&hist[r2 >> 1], 1u << ((r2 & 1) << 4));
            if ((u32)r3 < (u32)qN) atomicAdd(&hist[r3 >> 1], 1u << ((r3 & 1) << 4));
        }
        for (; e < e1; e += 256) {
            int r = row[e] - lo;
            if ((u32)r < (u32)qN) atomicAdd(&hist[r >> 1], 1u << ((r & 1) << 4));
        }
        __syncthreads();
        u32* dst = hist_part + (size_t)hb * QW;
        for (int i = tid; i < QW; i += 256) dst[i] = hist[i];
    } else {
        // ---- stats0: column sums/sumsq over x (K=256) + fused f32->bf16 ----
        float* sh = (float*)smem;
        const int K = H_IN;
        const int csz = 2 * H_IN;
        sh[tid] = 0.f;
        sh[tid + 256] = 0.f;
        __syncthreads();
        int sb = bx - NSLICE - 4 * HSL;
        int gid = sb * 256 + tid;
        int stride = SBLK * 256;
        int c0 = (tid * 4) & (H_IN - 1);
        float s0=0.f,s1=0.f,s2=0.f,s3=0.f, q0=0.f,q1=0.f,q2=0.f,q3=0.f;
        const float4* A4 = (const float4*)x;
        ushort4* X4 = (ushort4*)xb;
        auto proc = [&](int idx, float4 v) {
            ushort4 xv;
            xv.x = f2b(v.x); xv.y = f2b(v.y); xv.z = f2b(v.z); xv.w = f2b(v.w);
            X4[idx] = xv;
            s0 += v.x; q0 += v.x * v.x;
            s1 += v.y; q1 += v.y * v.y;
            s2 += v.z; q2 += v.z * v.z;
            s3 += v.w; q3 += v.w * v.w;
        };
        int i = gid;
        for (; i + 3 * stride < total4; i += 4 * stride) {
            float4 v0 = A4[i];
            float4 v1 = A4[i + stride];
            float4 v2 = A4[i + 2 * stride];
            float4 v3 = A4[i + 3 * stride];
            proc(i, v0);
            proc(i + stride, v1);
            proc(i + 2 * stride, v2);
            proc(i + 3 * stride, v3);
        }
        for (; i < total4; i += stride) proc(i, A4[i]);
        atomicAdd(&sh[c0],     s0); atomicAdd(&sh[K + c0],     q0);
        atomicAdd(&sh[c0 + 1], s1); atomicAdd(&sh[K + c0 + 1], q1);
        atomicAdd(&sh[c0 + 2], s2); atomicAdd(&sh[K + c0 + 2], q2);
        atomicAdd(&sh[c0 + 3], s3); atomicAdd(&sh[K + c0 + 3], q3);
        __syncthreads();
        float* dst = statsA + (size_t)(sb & (NCOPY - 1)) * csz;
        for (int i2 = tid; i2 < csz; i2 += 256) atomicAdd(&dst[i2], sh[i2]);
    }
}

// ---------------- prep_k: scatter role | dinv role (hist reduce) | fold0 role ----------------
// grid = NSLICE + DB + H.
__global__ __launch_bounds__(256) void prep_k(const int* __restrict__ row,
                                              const int* __restrict__ col,
                                              const u32* __restrict__ bcnt_part,
                                              u32* __restrict__ bbase,
                                              u32* __restrict__ ebuf,
                                              const u32* __restrict__ hist_part,
                                              float* __restrict__ dinv,
                                              const float* __restrict__ W,
                                              const float* __restrict__ stats_mc,
                                              const float* __restrict__ g,
                                              const float* __restrict__ bcoef,
                                              const float* __restrict__ bias,
                                              u16* __restrict__ Wt,
                                              float* __restrict__ bp,
                                              int E, int N, int DB, int QW, int qN) {
    int tid = threadIdx.x;
    int bx = blockIdx.x;
    if (bx < NSLICE) {
        // ---- scatter: rebuild per-slice cursor = bbase[b] + prefix over earlier slices ----
        __shared__ u32 sc[256];
        __shared__ u32 cur[256];
        int s = bx;
        u32 tot = 0, pre = 0;
        for (int t = 0; t < NSLICE; ++t) {
            u32 v = bcnt_part[t * 256 + tid];   // coalesced, L2-resident (256KB)
            tot += v;
            if (t < s) pre += v;
        }
        sc[tid] = tot;
        __syncthreads();
        for (int o = 1; o < 256; o <<= 1) {
            u32 xv = (tid >= o) ? sc[tid - o] : 0;
            __syncthreads();
            sc[tid] += xv;
            __syncthreads();
        }
        u32 base = sc[tid] - tot;               // exclusive bucket base
        if (s == 0) {
            bbase[tid] = base;
            if (tid == 255) bbase[256] = sc[255];   // == E
        }
        cur[tid] = base + pre;
        __syncthreads();
        int len = (E + NSLICE - 1) / NSLICE;
        int e0 = s * len;
        int e1 = min(e0 + len, E);
        for (int e = e0 + tid; e < e1; e += 256) {
            u32 r = (u32)row[e];
            u32 c = (u32)col[e];
            u32 pos = atomicAdd(&cur[c >> 8], 1u);
            ebuf[pos] = r | ((c & 255u) << 16);
        }
    } else if (bx < NSLICE + DB) {
        // ---- dinv: reduce quarter histograms across HSL slices ----
        int w = (bx - NSLICE) * 256 + tid;
        if (w < 4 * QW) {
            int qq = w / QW;
            int lw = w - qq * QW;
            u32 v = 0;
            for (int s = 0; s < HSL; ++s)
                v += hist_part[(size_t)(s * 4 + qq) * QW + lw];
            int n = qq * qN + 2 * lw;
            if (n < N)     dinv[n]     = rsqrtf((float)(v & 0xFFFF) + 1.0f);
            if (n + 1 < N) dinv[n + 1] = rsqrtf((float)(v >> 16) + 1.0f);
        }
    } else {
        // ---- fold0: BN-fold W_feat (K=256) using statsA ----
        int j = bx - NSLICE - DB;
        int k = tid;
        const int K = H_IN;
        const int csz = 2 * H_IN;
        float sum = 0.f, sumsq = 0.f;
#pragma unroll
        for (int c = 0; c < NCOPY; ++c) {
            sum   += stats_mc[(size_t)c * csz + k];
            sumsq += stats_mc[(size_t)c * csz + K + k];
        }
        float mu = sum / (float)N;
        float var = sumsq / (float)N - mu * mu;
        float sK = g[k] * rsqrtf(var + BN_EPS);
        float tK = bcoef[k] - mu * sK;
        float w = W[(size_t)k * H + j];
        Wt[(size_t)j * K + k] = f2b(sK * w);    // transposed: row j contiguous in k
        __shared__ float red[256];
        red[k] = tK * w;
        __syncthreads();
        for (int o = 128; o > 0; o >>= 1) {
            if (k < o) red[k] += red[k + o];
            __syncthreads();
        }
        if (k == 0) bp[j] = bias[j] + red[0];
    }
}

// ---------------- fold for layers 1..3 (K=128, blockDim=K) ----------------
__global__ void fold_k(const float* __restrict__ W, const float* __restrict__ stats_mc,
                       const float* __restrict__ g, const float* __restrict__ b,
                       const float* __restrict__ bias, u16* __restrict__ Wt,
                       float* __restrict__ bp, int N, int K) {
    int j = blockIdx.x;
    int k = threadIdx.x;
    int csz = 2 * K;
    float sum = 0.f, sumsq = 0.f;
#pragma unroll
    for (int c = 0; c < NCOPY; ++c) {
        sum   += stats_mc[(size_t)c * csz + k];
        sumsq += stats_mc[(size_t)c * csz + K + k];
    }
    float mu = sum / (float)N;
    float var = sumsq / (float)N - mu * mu;
    float s = g[k] * rsqrtf(var + BN_EPS);
    float t = b[k] - mu * s;
    float w = W[(size_t)k * H + j];
    Wt[(size_t)j * K + k] = f2b(s * w);
    __shared__ float red[256];
    red[k] = t * w;
    __syncthreads();
    for (int o = blockDim.x >> 1; o > 0; o >>= 1) {
        if (k < o) red[k] += red[k + o];
        __syncthreads();
    }
    if (k == 0) bp[j] = bias[j] + red[0];
}

// ---------------- MFMA GEMM (+ optional sortb role for layer 0) ----------------
template<int KT, int WITH_SORT>   // KT = K/32
__global__ __launch_bounds__(256) void gemm_mfma_k(const u16* __restrict__ Ab,
                                                   const u16* __restrict__ Wt,
                                                   u16* __restrict__ Yb, int M,
                                                   float* __restrict__ stats_z,
                                                   const u32* __restrict__ ebuf,
                                                   const u32* __restrict__ bbase,
                                                   int* __restrict__ rowptr,
                                                   u16* __restrict__ esrc, int N) {
    int tid = threadIdx.x;
    if constexpr (WITH_SORT != 0) {
        if (blockIdx.x >= GEMMB) {
            // ---- sortb role: per-bucket counting sort -> exact CSR ----
            __shared__ u32 est[SMAX];
            __shared__ u32 hist[256], scanv[256], cur[256];
            int b = blockIdx.x - GEMMB;
            u32 base = bbase[b];
            int size = (int)(bbase[b + 1] - base);
            int st = min(size, SMAX);
            hist[tid] = 0;
            __syncthreads();
            for (int i = tid; i < st; i += 256) {
                u32 e = ebuf[base + i];
                est[i] = e;
                atomicAdd(&hist[(e >> 16) & 255u], 1u);
            }
            for (int i = SMAX + tid; i < size; i += 256) {
                u32 e = ebuf[base + i];
                atomicAdd(&hist[(e >> 16) & 255u], 1u);
            }
            __syncthreads();
            u32 own = hist[tid];
            scanv[tid] = own;
            __syncthreads();
            for (int o = 1; o < 256; o <<= 1) {
                u32 t = (tid >= o) ? scanv[tid - o] : 0;
                __syncthreads();
                scanv[tid] += t;
                __syncthreads();
            }
            u32 excl = scanv[tid] - own;
            int idx = (b << 8) + tid;
            if (idx <= N) rowptr[idx] = (int)(base + excl);
            cur[tid] = excl;
            __syncthreads();
            for (int i = tid; i < st; i += 256) {
                u32 e = est[i];
                u32 pos = atomicAdd(&cur[(e >> 16) & 255u], 1u);
                esrc[base + pos] = (u16)(e & 0xFFFFu);
            }
            for (int i = SMAX + tid; i < size; i += 256) {
                u32 e = ebuf[base + i];
                u32 pos = atomicAdd(&cur[(e >> 16) & 255u], 1u);
                esrc[base + pos] = (u16)(e & 0xFFFFu);
            }
            return;
        }
    }
    const int K = KT * 32;
    if (stats_z && blockIdx.x == 0) {
        for (int i = tid; i < STATS_FLOATS; i += 256) stats_z[i] = 0.f;
    }
    int w = tid >> 6;
    int lane = tid & 63;
    int m16 = lane & 15;
    int q = lane >> 4;

    bf16x8 bfrag[KT][2];
#pragma unroll
    for (int t = 0; t < KT; ++t)
#pragma unroll
        for (int p = 0; p < 2; ++p) {
            int ncol = 32 * w + 16 * p + m16;
            bfrag[t][p] = *(const bf16x8*)(Wt + (size_t)ncol * K + 32 * t + 8 * q);
        }

    int nchunk = M >> 4;
    for (int c = blockIdx.x; c < nchunk; c += GEMMB) {
        int m0 = c << 4;
        const u16* Arow = Ab + (size_t)(m0 + m16) * K + 8 * q;
        bf16x8 afrag[KT];
#pragma unroll
        for (int t = 0; t < KT; ++t)
            afrag[t] = *(const bf16x8*)(Arow + 32 * t);
        f32x4 acc0 = {0.f, 0.f, 0.f, 0.f}, acc1 = {0.f, 0.f, 0.f, 0.f};
#pragma unroll
        for (int t = 0; t < KT; ++t) {
            acc0 = __builtin_amdgcn_mfma_f32_16x16x32_bf16(afrag[t], bfrag[t][0], acc0, 0, 0, 0);
            acc1 = __builtin_amdgcn_mfma_f32_16x16x32_bf16(afrag[t], bfrag[t][1], acc1, 0, 0, 0);
        }
        u16* Crow = Yb + (size_t)(m0 + q * 4) * H + 32 * w + m16;
#pragma unroll
        for (int i = 0; i < 4; ++i) {
            Crow[(size_t)i * H]      = f2b(acc0[i]);
            Crow[(size_t)i * H + 16] = f2b(acc1[i]);
        }
    }
}

// ---------------- CSR aggregation (bf16 gather, u16 esrc, on-the-fly norm) ----------------
__global__ __launch_bounds__(256) void csragg_k(const int* __restrict__ rowptr,
                                                const u16* __restrict__ esrc,
                                                const u16* __restrict__ Yb,
                                                const float* __restrict__ dinv,
                                                const float* __restrict__ bp,
                                                u16* __restrict__ Ob,
                                                float* __restrict__ Of,
                                                float* __restrict__ stats_mc,
                                                int do_stats, int N) {
    __shared__ float sh[1024];                // 4 waves x 256 bins
    int tid = threadIdx.x;
    int node = blockIdx.x * 16 + (tid >> 4);
    int fl = tid & 15;
    float o[8] = {0.f,0.f,0.f,0.f,0.f,0.f,0.f,0.f};
    if (node < N) {
        const us8* Y8 = (const us8*)Yb;
        float dn = dinv[node];
        float acc[8];
        {
            us8 ys = Y8[(size_t)node * 16 + fl];
#pragma unroll
            for (int j = 0; j < 8; ++j) acc[j] = dn * b2f(ys[j]);
        }
        int s = rowptr[node], e = rowptr[node + 1];
        int p = s;
        for (; p + 3 < e; p += 4) {
            int s0 = esrc[p], s1 = esrc[p + 1], s2 = esrc[p + 2], s3 = esrc[p + 3];
            float n0 = dinv[s0], n1 = dinv[s1], n2 = dinv[s2], n3 = dinv[s3];
            us8 v0 = Y8[(size_t)s0 * 16 + fl];
            us8 v1 = Y8[(size_t)s1 * 16 + fl];
            us8 v2 = Y8[(size_t)s2 * 16 + fl];
            us8 v3 = Y8[(size_t)s3 * 16 + fl];
#pragma unroll
            for (int j = 0; j < 8; ++j) acc[j] += n0 * b2f(v0[j]);
#pragma unroll
            for (int j = 0; j < 8; ++j) acc[j] += n1 * b2f(v1[j]);
#pragma unroll
            for (int j = 0; j < 8; ++j) acc[j] += n2 * b2f(v2[j]);
#pragma unroll
            for (int j = 0; j < 8; ++j) acc[j] += n3 * b2f(v3[j]);
        }
        for (; p < e; ++p) {
            int s0 = esrc[p];
            float n0 = dinv[s0];
            us8 v0 = Y8[(size_t)s0 * 16 + fl];
#pragma unroll
            for (int j = 0; j < 8; ++j) acc[j] += n0 * b2f(v0[j]);
        }
        float4 b0 = ((const float4*)bp)[fl * 2];
        float4 b1 = ((const float4*)bp)[fl * 2 + 1];
        o[0] = b0.x + dn * acc[0]; o[1] = b0.y + dn * acc[1];
        o[2] = b0.z + dn * acc[2]; o[3] = b0.w + dn * acc[3];
        o[4] = b1.x + dn * acc[4]; o[5] = b1.y + dn * acc[5];
        o[6] = b1.z + dn * acc[6]; o[7] = b1.w + dn * acc[7];
        if (Of) {
            float4* O4 = (float4*)Of;
            O4[(size_t)node * 32 + fl * 2]     = make_float4(o[0], o[1], o[2], o[3]);
            O4[(size_t)node * 32 + fl * 2 + 1] = make_float4(o[4], o[5], o[6], o[7]);
        } else {
            us8 ov;
#pragma unroll
            for (int j = 0; j < 8; ++j) ov[j] = f2b(o[j]);
            *(us8*)(Ob + (size_t)node * H + fl * 8) = ov;
        }
    }
    if (do_stats) {
        float sv[16];
#pragma unroll
        for (int j = 0; j < 8; ++j) { sv[j] = o[j]; sv[8 + j] = o[j] * o[j]; }
#pragma unroll
        for (int j = 0; j < 16; ++j) {
            sv[j] += __shfl_xor(sv[j], 16, 64);
            sv[j] += __shfl_xor(sv[j], 32, 64);
        }
        int lane = tid & 63, wv = tid >> 6;
        if (lane < 16) {
            float* base = sh + wv * 256;
#pragma unroll
            for (int j = 0; j < 8; ++j) {
                base[fl * 8 + j]       = sv[j];
                base[128 + fl * 8 + j] = sv[8 + j];
            }
        }
        __syncthreads();
        float v = sh[tid] + sh[256 + tid] + sh[512 + tid] + sh[768 + tid];
        atomicAdd(&stats_mc[(size_t)(blockIdx.x & (NCOPY - 1)) * (2 * H) + tid], v);
    }
}

// ---------------- host ----------------
extern "C" void kernel_launch(void* const* d_in, const int* in_sizes, int n_in,
                              void* d_out, int out_size, void* d_ws, size_t ws_size,
                              hipStream_t stream) {
    const float* x     = (const float*)d_in[0];
    const int*   ei    = (const int*)d_in[1];
    const float* bnfg  = (const float*)d_in[2];
    const float* bnfb  = (const float*)d_in[3];
    const float* Wfeat = (const float*)d_in[4];
    const float* bfeat = (const float*)d_in[5];
    const float* bng   = (const float*)d_in[6];
    const float* bnb   = (const float*)d_in[7];
    const float* Ws    = (const float*)d_in[8];
    const float* bs    = (const float*)d_in[9];

    int N = in_sizes[0] / H_IN;      // 50000  (must be < 65536 for u16 esrc)
    int E = in_sizes[1] / 2;         // 800000
    const int* row = ei;
    const int* col = ei + E;

    int NB = (N + 255) >> 8;         // 196 buckets
    int QW = (N + 7) / 8;            // 6250 words per quarter histogram
    int qN = 2 * QW;                 // 12500 rows per quarter
    int DB = (4 * QW + 255) / 256;   // 98 dinv blocks

    char* p = (char*)d_ws;
    auto alloc = [&](size_t bytes) { char* r = p; p += (bytes + 63) & ~size_t(63); return r; };
    float* statsA    = (float*)alloc(STATS_FLOATS * 4);
    float* statsB    = (float*)alloc(STATS_FLOATS * 4);
    float* dinv      = (float*)alloc((size_t)N * 4);
    u16*   Wt        = (u16*)alloc(H_IN * H * 2);
    float* bp        = (float*)alloc(H * 4);
    u32*   hist_part = (u32*)alloc((size_t)4 * HSL * QW * 4);   // 6.4MB
    u32*   bcnt_part = (u32*)alloc(NSLICE * 256 * 4);
    u32*   bbase     = (u32*)alloc(257 * 4);
    int*   rowptr    = (int*)alloc((size_t)(N + 1) * 4);
    u32*   ebuf      = (u32*)alloc((size_t)E * 4);
    u16*   esrc      = (u16*)alloc((size_t)E * 2);
    u16*   xb        = (u16*)alloc((size_t)N * H_IN * 2);
    u16*   Yb        = (u16*)alloc((size_t)N * H * 2);
    u16*   ACTb      = (u16*)alloc((size_t)N * H * 2);

    float* out = (float*)d_out;

    // zero statsA + statsB (128KB)
    hipMemsetAsync(statsA, 0, (size_t)(2 * STATS_FLOATS) * 4, stream);

    // dynamic LDS: hist role needs QW words; stats needs 2KB; bcnt 1KB
    size_t lds_bytes = (size_t)QW * 4;
    if (lds_bytes < 2 * H_IN * 4) lds_bytes = 2 * H_IN * 4;

    // col bucket counts || row quarter-histograms || BN stats over x + x->bf16
    build_k<<<NSLICE + 4 * HSL + SBLK, 256, lds_bytes, stream>>>(row, col, hist_part,
                                                                 bcnt_part, x, xb, statsA,
                                                                 E, N * H_IN / 4, QW, qN);
    // scatter (per-block cursor rescan) || dinv (hist reduce) || fold0
    prep_k<<<NSLICE + DB + H, 256, 0, stream>>>(row, col, bcnt_part, bbase, ebuf,
                                                hist_part, dinv,
                                                Wfeat, statsA, bnfg, bnfb, bfeat, Wt, bp,
                                                E, N, DB, QW, qN);
    // layer 0 GEMM || per-bucket counting sort -> CSR
    gemm_mfma_k<8, 1><<<GEMMB + NB, 256, 0, stream>>>(xb, Wt, Yb, N, nullptr,
                                                      ebuf, bbase, rowptr, esrc, N);
    // layer 0 aggregation; stats for layer 1 -> statsB (zeroed by memset)
    csragg_k<<<(N + 15) / 16, 256, 0, stream>>>(rowptr, esrc, Yb, dinv, bp,
                                                ACTb, nullptr, statsB, 1, N);

    for (int l = 1; l < 4; ++l) {
        const float* W    = Ws + (size_t)(l - 1) * H * H;
        const float* bias = bs + (size_t)(l - 1) * H;
        const float* g    = bng + (size_t)(l - 1) * H;
        const float* bb   = bnb + (size_t)(l - 1) * H;
        float* sfold   = (l & 1) ? statsB : statsA;              // stats consumed by fold l
        float* szero   = (l == 1) ? statsA : (l == 2) ? statsB : nullptr;  // next csragg target
        float* starget = ((l + 1) & 1) ? statsB : statsA;        // csragg l writes here

        fold_k<<<H, H, 0, stream>>>(W, sfold, g, bb, bias, Wt, bp, N, H);
        gemm_mfma_k<4, 0><<<GEMMB, 256, 0, stream>>>(ACTb, Wt, Yb, N, szero,
                                                     nullptr, nullptr, nullptr, nullptr, N);
        csragg_k<<<(N + 15) / 16, 256, 0, stream>>>(rowptr, esrc, Yb, dinv, bp,
                                                    ACTb, (l == 3) ? out : nullptr,
                                                    starget, (l < 3) ? 1 : 0, N);
    }
}